// Round 1
// baseline (686.741 us; speedup 1.0000x reference)
//
#include <hip/hip_runtime.h>

#define TT 512
#define DD 16
#define HH 48
#define BTILE 16
#define NTHR 768   // 12 waves: one 16-col N-tile per wave (192 gate cols)

typedef short bf8v __attribute__((ext_vector_type(8)));   // 8 x bf16 bits
typedef float f32x4 __attribute__((ext_vector_type(4)));

__device__ __forceinline__ ushort bfb(float f) {
    return __builtin_bit_cast(ushort, (__bf16)f);
}

template<int CTRL>
__device__ __forceinline__ float dppq(float x) {
    int i = __builtin_bit_cast(int, x);
    i = __builtin_amdgcn_update_dpp(0, i, CTRL, 0xF, 0xF, true);
    return __builtin_bit_cast(float, i);
}

// y = A * rcp(1 + exp2(M*x)) + B   (sigmoid: A=1,M=-log2e,B=0; tanh: A=2,M=-2log2e,B=-1)
__device__ __forceinline__ float actf(float x, float A, float M, float Bc) {
    float e = __builtin_amdgcn_exp2f(M * x);
    return __builtin_fmaf(A, __builtin_amdgcn_rcpf(1.0f + e), Bc);
}

// LDS-only barrier: avoid the compiler's vmcnt(0) drain that would stall the
// in-flight x prefetch (global load) at every __syncthreads.
__device__ __forceinline__ void barrier_lds() {
    asm volatile("s_waitcnt lgkmcnt(0)\ns_barrier" ::: "memory");
}

struct Inv {
    const float* x;
    int b0, wave, xm, xq, xdst, af_o, rbase;
    bool t0w, t2w;
    int wA0_o, wA1h1_o, wA1h2_o;
    float bias0, bias1, aA, aM, aB;
    bf8v w0f0, w0f1, w1f0, w1f1, w1f2;   // weight B-fragments, register-resident
};

template<int P>
__device__ __forceinline__ void lstm_step(const Inv& iv, int t,
        ushort (&A0u)[2][1024], ushort (&A1u)[2][1536],
        float4& xreg, float* c0, float* c1, float* h2v)
{
    // stage x_t (loaded 2 steps ago) into A0[P] fragment-order slots; prefetch x_{t+2}
    if (iv.wave == 0) {
        ushort4 s;
        s.x = bfb(xreg.x); s.y = bfb(xreg.y); s.z = bfb(xreg.z); s.w = bfb(xreg.w);
        *(ushort4*)&A0u[P][iv.xdst] = s;
        if (t + 2 < TT) {
            const float* xp = iv.x + ((size_t)(iv.b0 + iv.xm) * TT + (t + 2)) * DD + iv.xq * 4;
            xreg = *(const float4*)xp;
        }
    }
    barrier_lds();   // x_t + h0_t (A0[P]) + h2_{t-1} (A1[P]) visible

    // ---- layer 0: gates = [x_t | h0] x W  (K=64) ----
    bf8v a0 = *(const bf8v*)&A0u[P][iv.af_o];
    bf8v a1 = *(const bf8v*)&A0u[P][512 + iv.af_o];
    f32x4 acc = {iv.bias0, iv.bias0, iv.bias0, iv.bias0};
    acc = __builtin_amdgcn_mfma_f32_16x16x32_bf16(a0, iv.w0f0, acc, 0, 0, 0);
    acc = __builtin_amdgcn_mfma_f32_16x16x32_bf16(a1, iv.w0f1, acc, 0, 0, 0);

    float h1v[4];
#pragma unroll
    for (int r = 0; r < 4; ++r) {
        float a  = actf(acc[r], iv.aA, iv.aM, iv.aB);   // own gate type activated
        float q1 = dppq<0xB1>(a);                        // xor1 within quad
        float q2 = dppq<0x4E>(a);                        // xor2
        float q3 = dppq<0x1B>(a);                        // xor3
        float ig = a * q2;                               // i*g on lanes ty==0,2
        float fv = iv.t0w ? q1 : q3;                     // sigma(f)
        float ov = iv.t0w ? q3 : q1;                     // sigma(o)
        float c  = __builtin_fmaf(fv, c0[r], ig);
        c0[r] = c;
        float tc = actf(c, 2.0f, -2.8853900817779268f, -1.0f);  // tanh
        h1v[r] = ov * tc;
    }
    if (iv.t0w) {            // h1 -> next step's A0 (h0 slot)
#pragma unroll
        for (int r = 0; r < 4; ++r) A0u[P ^ 1][iv.wA0_o + (iv.rbase + r) * 8] = bfb(h1v[r]);
    } else if (iv.t2w) {     // h1 -> this step's A1 (layer-1 input slot)
#pragma unroll
        for (int r = 0; r < 4; ++r) A1u[P][iv.wA1h1_o + (iv.rbase + r) * 8] = bfb(h1v[r]);
    }
    barrier_lds();   // h1 visible in A1[P]

    // ---- layer 1: gates = [h1 | h2_{t-1}] x W  (K=96) ----
    bf8v g0 = *(const bf8v*)&A1u[P][iv.af_o];
    bf8v g1 = *(const bf8v*)&A1u[P][512 + iv.af_o];
    bf8v g2 = *(const bf8v*)&A1u[P][1024 + iv.af_o];
    f32x4 acd = {iv.bias1, iv.bias1, iv.bias1, iv.bias1};
    acd = __builtin_amdgcn_mfma_f32_16x16x32_bf16(g0, iv.w1f0, acd, 0, 0, 0);
    acd = __builtin_amdgcn_mfma_f32_16x16x32_bf16(g1, iv.w1f1, acd, 0, 0, 0);
    acd = __builtin_amdgcn_mfma_f32_16x16x32_bf16(g2, iv.w1f2, acd, 0, 0, 0);

#pragma unroll
    for (int r = 0; r < 4; ++r) {
        float a  = actf(acd[r], iv.aA, iv.aM, iv.aB);
        float q1 = dppq<0xB1>(a);
        float q2 = dppq<0x4E>(a);
        float q3 = dppq<0x1B>(a);
        float ig = a * q2;
        float fv = iv.t0w ? q1 : q3;
        float ov = iv.t0w ? q3 : q1;
        float c  = __builtin_fmaf(fv, c1[r], ig);
        c1[r] = c;
        float tc = actf(c, 2.0f, -2.8853900817779268f, -1.0f);
        h2v[r] = ov * tc;
    }
    if (iv.t0w) {            // h2 -> next step's A1 (recurrent slot)
#pragma unroll
        for (int r = 0; r < 4; ++r) A1u[P ^ 1][iv.wA1h2_o + (iv.rbase + r) * 8] = bfb(h2v[r]);
    }
}

__global__ __launch_bounds__(NTHR)
void lstm_kernel(const float* __restrict__ x,
                 const float* __restrict__ Wih0, const float* __restrict__ Whh0,
                 const float* __restrict__ bih0, const float* __restrict__ bhh0,
                 const float* __restrict__ Wih1, const float* __restrict__ Whh1,
                 const float* __restrict__ bih1, const float* __restrict__ bhh1,
                 const float* __restrict__ fcw, const float* __restrict__ fcb,
                 float* __restrict__ out)
{
    __shared__ alignas(16) ushort A0u[2][1024];  // [kgroup(8)][m(16)][j(8)] bf16, dbuf
    __shared__ alignas(16) ushort A1u[2][1536];  // [kgroup(12)][m(16)][j(8)] bf16, dbuf
    __shared__ float outl[16][48];

    const int tid  = threadIdx.x;
    const int lane = tid & 63;
    const int wave = tid >> 6;            // 0..11 = N-tile index
    const int b0   = blockIdx.x * BTILE;

    const int colq = lane & 15;
    const int col  = wave * 16 + colq;    // interleaved gate col = 4*u + type
    const int u    = col >> 2;            // h-unit 0..47
    const int ty   = col & 3;             // 0:i 1:f 2:g 3:o
    const int quad = lane >> 4;

    Inv iv;
    iv.x = x; iv.b0 = b0; iv.wave = wave;
    iv.xm = lane >> 2; iv.xq = lane & 3;
    iv.xdst = (iv.xq >> 1) * 128 + iv.xm * 8 + (iv.xq & 1) * 4;
    iv.af_o = quad * 128 + colq * 8;      // A-fragment read offset (conflict-free b128)
    iv.rbase = quad * 4;
    iv.t0w = (ty == 0);
    iv.t2w = (ty == 2);
    {
        const int k0 = 16 + u;
        iv.wA0_o   = (k0 >> 3) * 128 + (k0 & 7);
        iv.wA1h1_o = (u  >> 3) * 128 + (u  & 7);
        const int k2 = 48 + u;
        iv.wA1h2_o = (k2 >> 3) * 128 + (k2 & 7);
    }
    const int gi = ty * 48 + u;           // original (PyTorch-order) gate row
    iv.bias0 = bih0[gi] + bhh0[gi];
    iv.bias1 = bih1[gi] + bhh1[gi];
    const float L2E = 1.4426950408889634f;
    const bool isg = (ty == 2);
    iv.aA = isg ? 2.0f : 1.0f;
    iv.aM = isg ? -2.0f * L2E : -L2E;
    iv.aB = isg ? -1.0f : 0.0f;

    // ---- gather step-invariant weight B-fragments into registers ----
    {
        bf8v w;
#pragma unroll
        for (int j = 0; j < 8; ++j) {     // layer0 ks=0: k in [0,32)
            int k = quad * 8 + j;
            float v = (k < 16) ? Wih0[gi * 16 + k] : Whh0[gi * 48 + (k - 16)];
            w[j] = (short)bfb(v);
        }
        iv.w0f0 = w;
#pragma unroll
        for (int j = 0; j < 8; ++j) {     // layer0 ks=1: k in [32,64) -> Whh0
            int k = 32 + quad * 8 + j;
            w[j] = (short)bfb(Whh0[gi * 48 + (k - 16)]);
        }
        iv.w0f1 = w;
#pragma unroll
        for (int j = 0; j < 8; ++j) {     // layer1 ks=0: k in [0,32) -> Wih1
            int k = quad * 8 + j;
            w[j] = (short)bfb(Wih1[gi * 48 + k]);
        }
        iv.w1f0 = w;
#pragma unroll
        for (int j = 0; j < 8; ++j) {     // layer1 ks=1: k in [32,64)
            int k = 32 + quad * 8 + j;
            float v = (k < 48) ? Wih1[gi * 48 + k] : Whh1[gi * 48 + (k - 48)];
            w[j] = (short)bfb(v);
        }
        iv.w1f1 = w;
#pragma unroll
        for (int j = 0; j < 8; ++j) {     // layer1 ks=2: k in [64,96) -> Whh1
            int k = 64 + quad * 8 + j;
            w[j] = (short)bfb(Whh1[gi * 48 + (k - 48)]);
        }
        iv.w1f2 = w;
    }

    // zero h-state slots of buffer 0 (x slots are written by wave0 pre-barrier: don't race them)
    for (int i = tid; i < 768; i += NTHR)  A0u[0][256 + i] = 0;
    for (int i = tid; i < 1536; i += NTHR) A1u[0][i] = 0;

    // x prefetch pipeline (distance 2)
    float4 xa = {0, 0, 0, 0}, xb = {0, 0, 0, 0};
    if (wave == 0) {
        const float* xp = x + ((size_t)(b0 + iv.xm) * TT) * DD + iv.xq * 4;
        xa = *(const float4*)xp;          // x_0
        xb = *(const float4*)(xp + DD);   // x_1
    }

    float c0[4] = {0, 0, 0, 0}, c1[4] = {0, 0, 0, 0};
    float h2v[4] = {0, 0, 0, 0};

    for (int t = 0; t < TT; t += 2) {
        lstm_step<0>(iv, t,     A0u, A1u, xa, c0, c1, h2v);
        lstm_step<1>(iv, t + 1, A0u, A1u, xb, c0, c1, h2v);
    }

    // ---- epilogue: logits = h2_last @ fc_w^T + fc_b; sigmoid ----
    if (iv.t0w) {
#pragma unroll
        for (int r = 0; r < 4; ++r) outl[iv.rbase + r][u] = h2v[r];
    }
    __syncthreads();
    if (tid < 16) {
        float s = fcb[0];
        for (int uu = 0; uu < HH; ++uu) s = __builtin_fmaf(outl[tid][uu], fcw[uu], s);
        out[b0 + tid] = actf(s, 1.0f, -L2E, 0.0f);
    }
}

extern "C" void kernel_launch(void* const* d_in, const int* in_sizes, int n_in,
                              void* d_out, int out_size, void* d_ws, size_t ws_size,
                              hipStream_t stream) {
    const float* x    = (const float*)d_in[0];
    const float* Wih0 = (const float*)d_in[1];
    const float* Whh0 = (const float*)d_in[2];
    const float* bih0 = (const float*)d_in[3];
    const float* bhh0 = (const float*)d_in[4];
    const float* Wih1 = (const float*)d_in[5];
    const float* Whh1 = (const float*)d_in[6];
    const float* bih1 = (const float*)d_in[7];
    const float* bhh1 = (const float*)d_in[8];
    const float* fcw  = (const float*)d_in[9];
    const float* fcb  = (const float*)d_in[10];
    lstm_kernel<<<128, NTHR, 0, stream>>>(x, Wih0, Whh0, bih0, bhh0,
                                          Wih1, Whh1, bih1, bhh1, fcw, fcb,
                                          (float*)d_out);
}

// Round 2
// 548.430 us; speedup vs baseline: 1.2522x; 1.2522x over previous
//
#include <hip/hip_runtime.h>

#define TT 512
#define DD 16
#define HH 48
#define NTHR 768   // 12 waves: one 16-col N-tile per wave (192 interleaved gate cols)

typedef short bf8v __attribute__((ext_vector_type(8)));   // 8 x bf16 bits
typedef float f32x4 __attribute__((ext_vector_type(4)));

__device__ __forceinline__ ushort bfb(float f) {
    return __builtin_bit_cast(ushort, (__bf16)f);
}

template<int CTRL>
__device__ __forceinline__ float dppq(float x) {
    int i = __builtin_bit_cast(int, x);
    i = __builtin_amdgcn_update_dpp(0, i, CTRL, 0xF, 0xF, true);
    return __builtin_bit_cast(float, i);
}

// y = A*rcp(1+exp2(M*x)) + B  (sigmoid: A=1,M=-log2e,B=0; tanh: A=2,M=-2log2e,B=-1)
__device__ __forceinline__ float actf(float x, float A, float M, float Bc) {
    float e = __builtin_amdgcn_exp2f(M * x);
    return __builtin_fmaf(A, __builtin_amdgcn_rcpf(1.0f + e), Bc);
}

// LDS-only barrier: avoid the vmcnt(0) drain __syncthreads would force (keeps
// the x prefetch global loads in flight across iterations).
__device__ __forceinline__ void barrier_lds() {
    asm volatile("s_waitcnt lgkmcnt(0)\ns_barrier" ::: "memory");
}

__global__ __launch_bounds__(NTHR)
void lstm_kernel(const float* __restrict__ x,
                 const float* __restrict__ Wih0, const float* __restrict__ Whh0,
                 const float* __restrict__ bih0, const float* __restrict__ bhh0,
                 const float* __restrict__ Wih1, const float* __restrict__ Whh1,
                 const float* __restrict__ bih1, const float* __restrict__ bhh1,
                 const float* __restrict__ fcw, const float* __restrict__ fcb,
                 float* __restrict__ out)
{
    // A-operand staging, fragment-order: off(k,m) = (k>>3)*128 + m*8 + (k&7)
    __shared__ alignas(16) ushort A0u[2][1024];  // L0 A = [x(k0..15) | h1prev(k16..63)]
    __shared__ alignas(16) ushort A1u[2][1536];  // L1 A = [h1(k0..47) | h2prev(k48..95)]
    __shared__ float outl[16][48];

    const int tid  = threadIdx.x;
    const int lane = tid & 63;
    const int wave = tid >> 6;
    const int b0   = blockIdx.x * 16;

    const int colq = lane & 15;
    const int quad = lane >> 4;
    const int ty   = colq & 3;            // gate type 0:i 1:f 2:g 3:o
    const int u    = wave * 4 + (colq >> 2);   // h-unit 0..47
    const int mrow = quad * 4 + ty;       // cell row this lane owns post-transpose

    const int af_o = quad * 128 + colq * 8;    // A-frag read offset (ushorts)
    const int wA0_h1 = ((16 + u) >> 3) * 128 + mrow * 8 + ((16 + u) & 7);
    const int wA1_h1 = ((u) >> 3) * 128 + mrow * 8 + (u & 7);
    const int wA1_h2 = ((48 + u) >> 3) * 128 + mrow * 8 + ((48 + u) & 7);
    const bool o1 = (ty & 1) != 0;
    const bool o2 = (ty & 2) != 0;

    const int gi = ty * 48 + u;           // PyTorch gate row (i,f,g,o blocks of 48)
    const float L2E = 1.4426950408889634f;
    const bool isg = (ty == 2);
    const float aA = isg ? 2.0f : 1.0f;
    const float aM = isg ? -2.0f * L2E : -L2E;
    const float aB = isg ? -1.0f : 0.0f;
    const float b0s = bih0[gi] + bhh0[gi];
    const float b1s = bih1[gi] + bhh1[gi];
    const f32x4 bias0 = {b0s, b0s, b0s, b0s};
    const f32x4 bias1 = {b1s, b1s, b1s, b1s};

    // ---- step-invariant weight B-fragments in registers ----
    bf8v w0f0, w0f1, w1f0, w1f1, w1f2;
    {
        bf8v w;
#pragma unroll
        for (int j = 0; j < 8; ++j) {     // L0 k 0..31
            int k = quad * 8 + j;
            float v = (k < 16) ? Wih0[gi * 16 + k] : Whh0[gi * 48 + (k - 16)];
            w[j] = (short)bfb(v);
        }
        w0f0 = w;
#pragma unroll
        for (int j = 0; j < 8; ++j) {     // L0 k 32..63 -> Whh0
            int k = 32 + quad * 8 + j;
            w[j] = (short)bfb(Whh0[gi * 48 + (k - 16)]);
        }
        w0f1 = w;
#pragma unroll
        for (int j = 0; j < 8; ++j) {     // L1 k 0..31 -> Wih1
            int k = quad * 8 + j;
            w[j] = (short)bfb(Wih1[gi * 48 + k]);
        }
        w1f0 = w;
#pragma unroll
        for (int j = 0; j < 8; ++j) {     // L1 k 32..63
            int k = 32 + quad * 8 + j;
            float v = (k < 48) ? Wih1[gi * 48 + k] : Whh1[gi * 48 + (k - 48)];
            w[j] = (short)bfb(v);
        }
        w1f1 = w;
#pragma unroll
        for (int j = 0; j < 8; ++j) {     // L1 k 64..95 -> Whh1
            int k = 64 + quad * 8 + j;
            w[j] = (short)bfb(Whh1[gi * 48 + (k - 48)]);
        }
        w1f2 = w;
    }

    // ---- x staging: waves 8..11, one float per lane per step ----
    const bool stg  = (wave >= 8);
    const int  srow = (wave - 8) * 4 + quad;
    const int  sd   = lane & 15;
    const int  sdst = (sd >> 3) * 128 + srow * 8 + (sd & 7);
    const float* sptr = x + (size_t)(b0 + srow) * TT * DD + sd;

    // ---- init: zero h1prev region of A0[0], all of A1[0]; stage x0; preload x1,x2 ----
    ((uint*)&A1u[0][0])[tid] = 0;                       // 768 uints = 1536 ushorts
    if (tid < 384) ((uint*)&A0u[0][256])[tid] = 0;      // h region k16..63
    float r0 = 0.f, r1 = 0.f;
    if (stg) {
        float v = sptr[0];
        r0 = sptr[DD];          // x(1)
        r1 = sptr[2 * DD];      // x(2)
        A0u[0][sdst] = bfb(v);  // x(0)
    }
    __syncthreads();

    float c0 = 0.f, c1 = 0.f, h2fin = 0.f;

    // one cell update: activate own-type 4 rows, 4x4 quad transpose, update 1 cell
    auto cell = [&](const f32x4& acc, float& c) -> float {
        float v0 = actf(acc[0], aA, aM, aB);
        float v1 = actf(acc[1], aA, aM, aB);
        float v2 = actf(acc[2], aA, aM, aB);
        float v3 = actf(acc[3], aA, aM, aB);
        // stage 1: lane-xor1, slot pairs (0,1),(2,3)
        float t0 = o1 ? v0 : v1;
        float t1 = o1 ? v2 : v3;
        float y0 = dppq<0xB1>(t0);
        float y1 = dppq<0xB1>(t1);
        v0 = o1 ? y0 : v0;  v1 = o1 ? v1 : y0;
        v2 = o1 ? y1 : v2;  v3 = o1 ? v3 : y1;
        // stage 2: lane-xor2, slot pairs (0,2),(1,3)
        t0 = o2 ? v0 : v2;
        t1 = o2 ? v1 : v3;
        y0 = dppq<0x4E>(t0);
        y1 = dppq<0x4E>(t1);
        v0 = o2 ? y0 : v0;  v2 = o2 ? v2 : y0;
        v1 = o2 ? y1 : v1;  v3 = o2 ? v3 : y1;
        // v0=sig(i) v1=sig(f) v2=tanh(g) v3=sig(o) for row mrow, unit u
        float cn = __builtin_fmaf(v1, c, v0 * v2);
        c = cn;
        float tc = actf(cn, 2.0f, -2.8853900817779268f, -1.0f);
        return v3 * tc;
    };

    // iteration t: L0(t) + L1(t-1); reads A0[P],A1[P^1]; writes A0[P^1],A1[P]; 1 barrier
#define BODY(P, DOL1, t) { \
        bf8v a0 = *(const bf8v*)&A0u[P][af_o]; \
        bf8v a1 = *(const bf8v*)&A0u[P][512 + af_o]; \
        f32x4 acc0 = __builtin_amdgcn_mfma_f32_16x16x32_bf16(a0, w0f0, bias0, 0, 0, 0); \
        acc0 = __builtin_amdgcn_mfma_f32_16x16x32_bf16(a1, w0f1, acc0, 0, 0, 0); \
        f32x4 acc1; \
        if (DOL1) { \
            bf8v g0 = *(const bf8v*)&A1u[(P)^1][af_o]; \
            bf8v g1 = *(const bf8v*)&A1u[(P)^1][512 + af_o]; \
            bf8v g2 = *(const bf8v*)&A1u[(P)^1][1024 + af_o]; \
            acc1 = __builtin_amdgcn_mfma_f32_16x16x32_bf16(g0, w1f0, bias1, 0, 0, 0); \
            acc1 = __builtin_amdgcn_mfma_f32_16x16x32_bf16(g1, w1f1, acc1, 0, 0, 0); \
            acc1 = __builtin_amdgcn_mfma_f32_16x16x32_bf16(g2, w1f2, acc1, 0, 0, 0); \
        } \
        float h1 = cell(acc0, c0); \
        ushort hb1 = bfb(h1); \
        A0u[(P)^1][wA0_h1] = hb1; \
        A1u[P][wA1_h1] = hb1; \
        if (DOL1) { \
            h2fin = cell(acc1, c1); \
            A1u[P][wA1_h2] = bfb(h2fin); \
        } \
        if (stg) { \
            A0u[(P)^1][sdst] = bfb(r0); \
            r0 = r1; \
            int t3 = (t) + 3; if (t3 > TT - 1) t3 = TT - 1; \
            r1 = sptr[t3 * DD]; \
        } \
        barrier_lds(); \
    }

    BODY(0, false, 0)                       // L0(0) only
    for (int t = 1; t < TT - 1; t += 2) {   // t = 1,3,...,509
        BODY(1, true, t)
        BODY(0, true, t + 1)
    }
    BODY(1, true, TT - 1)                   // t=511: L0(511) + L1(510)

    // post-peel: L1(511) from A1(511) = buffer 1
    {
        bf8v g0 = *(const bf8v*)&A1u[1][af_o];
        bf8v g1 = *(const bf8v*)&A1u[1][512 + af_o];
        bf8v g2 = *(const bf8v*)&A1u[1][1024 + af_o];
        f32x4 acc1 = __builtin_amdgcn_mfma_f32_16x16x32_bf16(g0, w1f0, bias1, 0, 0, 0);
        acc1 = __builtin_amdgcn_mfma_f32_16x16x32_bf16(g1, w1f1, acc1, 0, 0, 0);
        acc1 = __builtin_amdgcn_mfma_f32_16x16x32_bf16(g2, w1f2, acc1, 0, 0, 0);
        h2fin = cell(acc1, c1);
    }

    // epilogue: each lane owns one (row, unit) of h2(T-1)
    outl[mrow][u] = h2fin;
    __syncthreads();
    if (tid < 16) {
        float s = fcb[0];
        for (int uu = 0; uu < HH; ++uu) s = __builtin_fmaf(outl[tid][uu], fcw[uu], s);
        out[b0 + tid] = actf(s, 1.0f, -L2E, 0.0f);
    }
#undef BODY
}

extern "C" void kernel_launch(void* const* d_in, const int* in_sizes, int n_in,
                              void* d_out, int out_size, void* d_ws, size_t ws_size,
                              hipStream_t stream) {
    const float* x    = (const float*)d_in[0];
    const float* Wih0 = (const float*)d_in[1];
    const float* Whh0 = (const float*)d_in[2];
    const float* bih0 = (const float*)d_in[3];
    const float* bhh0 = (const float*)d_in[4];
    const float* Wih1 = (const float*)d_in[5];
    const float* Whh1 = (const float*)d_in[6];
    const float* bih1 = (const float*)d_in[7];
    const float* bhh1 = (const float*)d_in[8];
    const float* fcw  = (const float*)d_in[9];
    const float* fcb  = (const float*)d_in[10];
    lstm_kernel<<<128, NTHR, 0, stream>>>(x, Wih0, Whh0, bih0, bhh0,
                                          Wih1, Whh1, bih1, bhh1, fcw, fcb,
                                          (float*)d_out);
}

// Round 3
// 464.769 us; speedup vs baseline: 1.4776x; 1.1800x over previous
//
#include <hip/hip_runtime.h>

#define TT 512
#define DD 16
#define HH 48
#define NTHR 768   // 12 waves: one 16-gate-row tile per wave (192 interleaved gate rows)

typedef short bf8v __attribute__((ext_vector_type(8)));   // 8 x bf16 bits
typedef float f32x4 __attribute__((ext_vector_type(4)));

__device__ __forceinline__ ushort bfb(float f) {
    return __builtin_bit_cast(ushort, (__bf16)f);
}

// y = A*rcp(1+exp2(M*x)) + B  (sigmoid: A=1,M=-log2e,B=0; tanh: A=2,M=-2log2e,B=-1)
__device__ __forceinline__ float actf(float x, float A, float M, float Bc) {
    float e = __builtin_amdgcn_exp2f(M * x);
    return __builtin_fmaf(A, __builtin_amdgcn_rcpf(1.0f + e), Bc);
}

// LDS-only barrier: avoid the vmcnt(0) drain __syncthreads would force (keeps
// the x prefetch global loads in flight across iterations).
__device__ __forceinline__ void barrier_lds() {
    asm volatile("s_waitcnt lgkmcnt(0)\ns_barrier" ::: "memory");
}

__global__ __launch_bounds__(NTHR)
void lstm_kernel(const float* __restrict__ x,
                 const float* __restrict__ Wih0, const float* __restrict__ Whh0,
                 const float* __restrict__ bih0, const float* __restrict__ bhh0,
                 const float* __restrict__ Wih1, const float* __restrict__ Whh1,
                 const float* __restrict__ bih1, const float* __restrict__ bhh1,
                 const float* __restrict__ fcw, const float* __restrict__ fcb,
                 float* __restrict__ out)
{
    // Activation staging (B-operand), fragment-order:
    //   off(k, n=batchcol) = (k>>3)*128 + n*8 + (k&7)   [ushort units]
    __shared__ alignas(16) ushort A0u[2][1024];  // L0 B = [x(k0..15) | h1prev(k16..63)]
    __shared__ alignas(16) ushort A1u[2][1536];  // L1 B = [h1(k0..47) | h2prev(k48..95)]
    __shared__ float outl[16][48];

    const int tid  = threadIdx.x;
    const int lane = tid & 63;
    const int wave = tid >> 6;
    const int b0   = blockIdx.x * 16;

    const int colq = lane & 15;           // batch col n (C/D + B-frag); gate row m (A-frag)
    const int quad = lane >> 4;
    const int u    = wave * 4 + quad;     // unit this lane owns in C/D: acc[r] = gate r of unit u

    const int af_o = quad * 128 + colq * 8;    // B-frag read offset (ushorts)
    const int wA0_h1 = ((16 + u) >> 3) * 128 + colq * 8 + ((16 + u) & 7);
    const int wA1_h1 = ((u) >> 3) * 128 + colq * 8 + (u & 7);
    const int wA1_h2 = ((48 + u) >> 3) * 128 + colq * 8 + ((48 + u) & 7);

    const float L2E = 1.4426950408889634f;

    // C-operand biases: lane owns unit u, acc[r] = gate type r (i,f,g,o)
    f32x4 bias0, bias1;
#pragma unroll
    for (int r = 0; r < 4; ++r) {
        bias0[r] = bih0[r * 48 + u] + bhh0[r * 48 + u];
        bias1[r] = bih1[r * 48 + u] + bhh1[r * 48 + u];
    }

    // ---- step-invariant weight A-fragments in registers ----
    // A-frag: lane holds A[m = colq][k = quad*8+j]; tile row m -> interleaved
    // gate row = 4*(wave*4 + (m>>2)) + (m&3)  -> original gate index gi:
    const int gi = (colq & 3) * 48 + wave * 4 + (colq >> 2);
    bf8v w0f0, w0f1, w1f0, w1f1, w1f2;
    {
        bf8v w;
#pragma unroll
        for (int j = 0; j < 8; ++j) {     // L0 k 0..31
            int k = quad * 8 + j;
            float v = (k < 16) ? Wih0[gi * 16 + k] : Whh0[gi * 48 + (k - 16)];
            w[j] = (short)bfb(v);
        }
        w0f0 = w;
#pragma unroll
        for (int j = 0; j < 8; ++j) {     // L0 k 32..63 -> Whh0
            int k = 32 + quad * 8 + j;
            w[j] = (short)bfb(Whh0[gi * 48 + (k - 16)]);
        }
        w0f1 = w;
#pragma unroll
        for (int j = 0; j < 8; ++j) {     // L1 k 0..31 -> Wih1
            int k = quad * 8 + j;
            w[j] = (short)bfb(Wih1[gi * 48 + k]);
        }
        w1f0 = w;
#pragma unroll
        for (int j = 0; j < 8; ++j) {     // L1 k 32..63
            int k = 32 + quad * 8 + j;
            float v = (k < 48) ? Wih1[gi * 48 + k] : Whh1[gi * 48 + (k - 48)];
            w[j] = (short)bfb(v);
        }
        w1f1 = w;
#pragma unroll
        for (int j = 0; j < 8; ++j) {     // L1 k 64..95 -> Whh1
            int k = 64 + quad * 8 + j;
            w[j] = (short)bfb(Whh1[gi * 48 + (k - 48)]);
        }
        w1f2 = w;
    }

    // ---- x staging: waves 8..11, one float per lane per step ----
    const bool stg  = (wave >= 8);
    const int  srow = (wave - 8) * 4 + quad;
    const int  sd   = lane & 15;
    const int  sdst = (sd >> 3) * 128 + srow * 8 + (sd & 7);
    const float* sptr = x + (size_t)(b0 + srow) * TT * DD + sd;

    // ---- init: zero h1prev region of A0[0], all of A1[0]; stage x0; preload x1,x2 ----
    ((uint*)&A1u[0][0])[tid] = 0;                       // 768 uints = 1536 ushorts
    if (tid < 384) ((uint*)&A0u[0][256])[tid] = 0;      // h region k16..63
    float r0 = 0.f, r1 = 0.f;
    if (stg) {
        float v = sptr[0];
        r0 = sptr[DD];          // x(1)
        r1 = sptr[2 * DD];      // x(2)
        A0u[0][sdst] = bfb(v);  // x(0)
    }
    __syncthreads();

    float c0 = 0.f, c1 = 0.f, h2fin = 0.f;

    // lane owns one cell (batch=colq, unit=u); acc = {i,f,g,o} pre-activations
    auto cell = [&](const f32x4& acc, float& c) -> float {
        float iv = actf(acc[0], 1.0f, -L2E, 0.0f);
        float fv = actf(acc[1], 1.0f, -L2E, 0.0f);
        float gv = actf(acc[2], 2.0f, -2.0f * L2E, -1.0f);
        float ov = actf(acc[3], 1.0f, -L2E, 0.0f);
        float cn = __builtin_fmaf(fv, c, iv * gv);
        c = cn;
        float tc = actf(cn, 2.0f, -2.0f * L2E, -1.0f);
        return ov * tc;
    };

    // iteration t: L0(t) + L1(t-1); reads A0[P],A1[P^1]; writes A0[P^1],A1[P]; 1 barrier
#define BODY(P, DOL1, t) { \
        bf8v a0 = *(const bf8v*)&A0u[P][af_o]; \
        bf8v a1 = *(const bf8v*)&A0u[P][512 + af_o]; \
        f32x4 acc0 = __builtin_amdgcn_mfma_f32_16x16x32_bf16(w0f0, a0, bias0, 0, 0, 0); \
        acc0 = __builtin_amdgcn_mfma_f32_16x16x32_bf16(w0f1, a1, acc0, 0, 0, 0); \
        f32x4 acc1; \
        if (DOL1) { \
            bf8v g0 = *(const bf8v*)&A1u[(P)^1][af_o]; \
            bf8v g1 = *(const bf8v*)&A1u[(P)^1][512 + af_o]; \
            bf8v g2 = *(const bf8v*)&A1u[(P)^1][1024 + af_o]; \
            acc1 = __builtin_amdgcn_mfma_f32_16x16x32_bf16(w1f0, g0, bias1, 0, 0, 0); \
            acc1 = __builtin_amdgcn_mfma_f32_16x16x32_bf16(w1f1, g1, acc1, 0, 0, 0); \
            acc1 = __builtin_amdgcn_mfma_f32_16x16x32_bf16(w1f2, g2, acc1, 0, 0, 0); \
        } \
        float h1 = cell(acc0, c0); \
        ushort hb1 = bfb(h1); \
        A0u[(P)^1][wA0_h1] = hb1; \
        A1u[P][wA1_h1] = hb1; \
        if (DOL1) { \
            h2fin = cell(acc1, c1); \
            A1u[P][wA1_h2] = bfb(h2fin); \
        } \
        if (stg) { \
            A0u[(P)^1][sdst] = bfb(r0); \
            r0 = r1; \
            int t3 = (t) + 3; if (t3 > TT - 1) t3 = TT - 1; \
            r1 = sptr[t3 * DD]; \
        } \
        barrier_lds(); \
    }

    BODY(0, false, 0)                       // L0(0) only
    for (int t = 1; t < TT - 1; t += 2) {   // t = 1,3,...,509
        BODY(1, true, t)
        BODY(0, true, t + 1)
    }
    BODY(1, true, TT - 1)                   // t=511: L0(511) + L1(510)

    // post-peel: L1(511) from A1(511) = buffer 1
    {
        bf8v g0 = *(const bf8v*)&A1u[1][af_o];
        bf8v g1 = *(const bf8v*)&A1u[1][512 + af_o];
        bf8v g2 = *(const bf8v*)&A1u[1][1024 + af_o];
        f32x4 acc1 = __builtin_amdgcn_mfma_f32_16x16x32_bf16(w1f0, g0, bias1, 0, 0, 0);
        acc1 = __builtin_amdgcn_mfma_f32_16x16x32_bf16(w1f1, g1, acc1, 0, 0, 0);
        acc1 = __builtin_amdgcn_mfma_f32_16x16x32_bf16(w1f2, g2, acc1, 0, 0, 0);
        h2fin = cell(acc1, c1);
    }

    // epilogue: each lane owns (batch=colq, unit=u) of h2(T-1)
    outl[colq][u] = h2fin;
    __syncthreads();
    if (tid < 16) {
        float s = fcb[0];
        for (int uu = 0; uu < HH; ++uu) s = __builtin_fmaf(outl[tid][uu], fcw[uu], s);
        out[b0 + tid] = actf(s, 1.0f, -L2E, 0.0f);
    }
#undef BODY
}

extern "C" void kernel_launch(void* const* d_in, const int* in_sizes, int n_in,
                              void* d_out, int out_size, void* d_ws, size_t ws_size,
                              hipStream_t stream) {
    const float* x    = (const float*)d_in[0];
    const float* Wih0 = (const float*)d_in[1];
    const float* Whh0 = (const float*)d_in[2];
    const float* bih0 = (const float*)d_in[3];
    const float* bhh0 = (const float*)d_in[4];
    const float* Wih1 = (const float*)d_in[5];
    const float* Whh1 = (const float*)d_in[6];
    const float* bih1 = (const float*)d_in[7];
    const float* bhh1 = (const float*)d_in[8];
    const float* fcw  = (const float*)d_in[9];
    const float* fcb  = (const float*)d_in[10];
    lstm_kernel<<<128, NTHR, 0, stream>>>(x, Wih0, Whh0, bih0, bhh0,
                                          Wih1, Whh1, bih1, bhh1, fcw, fcb,
                                          (float*)d_out);
}

// Round 5
// 308.927 us; speedup vs baseline: 2.2230x; 1.5045x over previous
//
#include <hip/hip_runtime.h>

#define TT 512
#define DD 16
#define HH 48
#define BT 8       // batch rows per block -> 256 blocks, one per CU
#define NTHR 768   // 12 waves: one 16-gate-row tile per wave (192 interleaved gate rows)

typedef short bf8v __attribute__((ext_vector_type(8)));   // 8 x bf16 bits
typedef float f32x4 __attribute__((ext_vector_type(4)));

__device__ __forceinline__ ushort bfb(float f) {
    return __builtin_bit_cast(ushort, (__bf16)f);
}

// y = A*rcp(1+exp2(M*x)) + B  (sigmoid: A=1,M=-log2e,B=0; tanh: A=2,M=-2log2e,B=-1)
__device__ __forceinline__ float actf(float x, float A, float M, float Bc) {
    float e = __builtin_amdgcn_exp2f(M * x);
    return __builtin_fmaf(A, __builtin_amdgcn_rcpf(1.0f + e), Bc);
}

// LDS-only barrier: avoid the vmcnt(0) drain __syncthreads would force (keeps
// the x prefetch global loads in flight across iterations).
__device__ __forceinline__ void barrier_lds() {
    asm volatile("s_waitcnt lgkmcnt(0)\ns_barrier" ::: "memory");
}

__global__ __launch_bounds__(NTHR)
void lstm_kernel(const float* __restrict__ x,
                 const float* __restrict__ Wih0, const float* __restrict__ Whh0,
                 const float* __restrict__ bih0, const float* __restrict__ bhh0,
                 const float* __restrict__ Wih1, const float* __restrict__ Whh1,
                 const float* __restrict__ bih1, const float* __restrict__ bhh1,
                 const float* __restrict__ fcw, const float* __restrict__ fcb,
                 float* __restrict__ out)
{
    // B-operand staging, fragment-order: off(k,n) = (k>>3)*128 + n*8 + (k&7) [ushorts]
    // A0u: L0 input  [x(k0..15) | h1prev(k16..63)],  batch b at col n = b   (cols 8..15 = 0)
    // A1u: L1 input  [h1(k0..47) | h2prev(k48..95)], batch b at col n = b+8 (cols 0..7  = 0)
    __shared__ alignas(16) ushort A0u[2][1024];
    __shared__ alignas(16) ushort A1u[2][1536];
    __shared__ float outl[BT][HH];

    const int tid  = threadIdx.x;
    const int lane = tid & 63;
    const int wave = tid >> 6;
    const int b0   = blockIdx.x * BT;

    const int colq = lane & 15;
    const int quad = lane >> 4;
    const int u    = wave * 4 + quad;     // unit owned in C/D: acc[r] = gate r of unit u
    const bool lo  = (colq < 8);          // lo: L0 cell (batch colq); hi: L1 cell (batch colq-8)

    const int af_o = quad * 128 + colq * 8;    // B-frag read offset (ushorts)
    // combined per-lane h write address into A1[P]:
    //   lo: h1 of batch colq  -> k = u,     col = colq+8
    //   hi: h2 of batch colq-8-> k = 48+u,  col = colq
    const int waddrA1 = lo
        ? ((u >> 3) * 128 + (colq + 8) * 8 + (u & 7))
        : (((48 + u) >> 3) * 128 + colq * 8 + ((48 + u) & 7));
    // lo-only h1prev write into A0[P^1]: k = 16+u, col = colq
    const int wA0 = ((16 + u) >> 3) * 128 + colq * 8 + ((16 + u) & 7);

    const float L2E = 1.4426950408889634f;

    // C-operand biases (all N cols get them; junk cols harmless)
    f32x4 bias0, bias1;
#pragma unroll
    for (int r = 0; r < 4; ++r) {
        bias0[r] = bih0[r * 48 + u] + bhh0[r * 48 + u];
        bias1[r] = bih1[r * 48 + u] + bhh1[r * 48 + u];
    }

    // ---- step-invariant weight A-fragments in registers ----
    // A-frag: lane holds A[m=colq][k=quad*8+j]; interleaved gate row -> PyTorch gi:
    const int gi = (colq & 3) * 48 + wave * 4 + (colq >> 2);
    bf8v w0f0, w0f1, w1f0, w1f1, w1f2;
    {
        bf8v w;
#pragma unroll
        for (int j = 0; j < 8; ++j) {     // L0 k 0..31
            int k = quad * 8 + j;
            float v = (k < 16) ? Wih0[gi * 16 + k] : Whh0[gi * 48 + (k - 16)];
            w[j] = (short)bfb(v);
        }
        w0f0 = w;
#pragma unroll
        for (int j = 0; j < 8; ++j) {     // L0 k 32..63 -> Whh0
            int k = 32 + quad * 8 + j;
            w[j] = (short)bfb(Whh0[gi * 48 + (k - 16)]);
        }
        w0f1 = w;
#pragma unroll
        for (int j = 0; j < 8; ++j) {     // L1 k 0..31 -> Wih1
            int k = quad * 8 + j;
            w[j] = (short)bfb(Wih1[gi * 48 + k]);
        }
        w1f0 = w;
#pragma unroll
        for (int j = 0; j < 8; ++j) {     // L1 k 32..63
            int k = 32 + quad * 8 + j;
            float v = (k < 48) ? Wih1[gi * 48 + k] : Whh1[gi * 48 + (k - 48)];
            w[j] = (short)bfb(v);
        }
        w1f1 = w;
#pragma unroll
        for (int j = 0; j < 8; ++j) {     // L1 k 64..95 -> Whh1
            int k = 64 + quad * 8 + j;
            w[j] = (short)bfb(Whh1[gi * 48 + (k - 48)]);
        }
        w1f2 = w;
    }

    // ---- x staging: waves 10..11, one float per lane per step (8 rows x 16 d) ----
    const bool stg  = (wave >= 10);
    const int  srow = (wave - 10) * 4 + quad;   // batch row 0..7 -> col srow
    const int  sd   = colq;
    const int  sdst = (sd >> 3) * 128 + srow * 8 + (sd & 7);
    const float* sptr = x + (size_t)(b0 + srow) * TT * DD + sd;

    // ---- init: zero both buffers fully (keeps unused cols at 0 forever) ----
    {
        uint* p0 = (uint*)A0u;
        for (int i = tid; i < 1024; i += NTHR) p0[i] = 0;
        uint* p1 = (uint*)A1u;
        for (int i = tid; i < 1536; i += NTHR) p1[i] = 0;
    }
    float r0 = 0.f, r1 = 0.f;
    __syncthreads();
    if (stg) {
        float v = sptr[0];
        r0 = sptr[DD];          // x(1)
        r1 = sptr[2 * DD];      // x(2)
        A0u[0][sdst] = bfb(v);  // x(0)
    }
    __syncthreads();

    float c = 0.f;   // lo: c0 state; hi: c1 state

    // iteration t: L0(t) + L1(t-1); reads A0[P],A1[P^1]; writes A0[P^1],A1[P]; 1 barrier.
    // Staging first: explicit vmcnt(0) guarantees r0/r1 (loads >=1 body old) have
    // landed before the ds_write consumes them — the compiler's waitcnt insertion
    // around our inline-asm barrier is not trusted for this loop-carried register
    // dependency (round-4 intermittent divergence). The new load then gets a full
    // body of latency hiding before the next barrier.
#define BODY(P, DOL1, t) { \
        if (stg) { \
            asm volatile("s_waitcnt vmcnt(0)" ::: "memory"); \
            A0u[(P)^1][sdst] = bfb(r0); \
            r0 = r1; \
            int t3 = (t) + 3; if (t3 > TT - 1) t3 = TT - 1; \
            r1 = sptr[t3 * DD]; \
        } \
        bf8v a0 = *(const bf8v*)&A0u[P][af_o]; \
        bf8v a1 = *(const bf8v*)&A0u[P][512 + af_o]; \
        f32x4 acc0 = __builtin_amdgcn_mfma_f32_16x16x32_bf16(w0f0, a0, bias0, 0, 0, 0); \
        acc0 = __builtin_amdgcn_mfma_f32_16x16x32_bf16(w0f1, a1, acc0, 0, 0, 0); \
        f32x4 pre; \
        if (DOL1) { \
            bf8v g0 = *(const bf8v*)&A1u[(P)^1][af_o]; \
            bf8v g1 = *(const bf8v*)&A1u[(P)^1][512 + af_o]; \
            bf8v g2 = *(const bf8v*)&A1u[(P)^1][1024 + af_o]; \
            f32x4 acc1 = __builtin_amdgcn_mfma_f32_16x16x32_bf16(w1f0, g0, bias1, 0, 0, 0); \
            acc1 = __builtin_amdgcn_mfma_f32_16x16x32_bf16(w1f1, g1, acc1, 0, 0, 0); \
            acc1 = __builtin_amdgcn_mfma_f32_16x16x32_bf16(w1f2, g2, acc1, 0, 0, 0); \
            pre[0] = lo ? acc0[0] : acc1[0]; \
            pre[1] = lo ? acc0[1] : acc1[1]; \
            pre[2] = lo ? acc0[2] : acc1[2]; \
            pre[3] = lo ? acc0[3] : acc1[3]; \
        } else { \
            pre = acc0; \
        } \
        float iv = actf(pre[0], 1.0f, -L2E, 0.0f); \
        float fv = actf(pre[1], 1.0f, -L2E, 0.0f); \
        float gv = actf(pre[2], 2.0f, -2.0f * L2E, -1.0f); \
        float ov = actf(pre[3], 1.0f, -L2E, 0.0f); \
        float cn = __builtin_fmaf(fv, c, iv * gv); \
        if (!DOL1) cn = lo ? cn : c;   /* peel: don't corrupt L1 state */ \
        c = cn; \
        float tc = actf(cn, 2.0f, -2.0f * L2E, -1.0f); \
        hv = ov * tc; \
        ushort hb = bfb(hv); \
        if (DOL1) { A1u[P][waddrA1] = hb; } \
        else if (lo) { A1u[P][waddrA1] = hb; } \
        if (lo) A0u[(P)^1][wA0] = hb; \
        barrier_lds(); \
    }

    float hv = 0.f;
    BODY(0, false, 0)                       // L0(0) only
    for (int t = 1; t < TT - 1; t += 2) {   // t = 1,3,...,509
        BODY(1, true, t)
        BODY(0, true, t + 1)
    }
    BODY(1, true, TT - 1)                   // t=511: L0(511) + L1(510)

    // post-peel: L1(511) from A1 buffer 1 (written by t=511 body)
    {
        bf8v g0 = *(const bf8v*)&A1u[1][af_o];
        bf8v g1 = *(const bf8v*)&A1u[1][512 + af_o];
        bf8v g2 = *(const bf8v*)&A1u[1][1024 + af_o];
        f32x4 acc1 = __builtin_amdgcn_mfma_f32_16x16x32_bf16(w1f0, g0, bias1, 0, 0, 0);
        acc1 = __builtin_amdgcn_mfma_f32_16x16x32_bf16(w1f1, g1, acc1, 0, 0, 0);
        acc1 = __builtin_amdgcn_mfma_f32_16x16x32_bf16(w1f2, g2, acc1, 0, 0, 0);
        float iv = actf(acc1[0], 1.0f, -L2E, 0.0f);
        float fv = actf(acc1[1], 1.0f, -L2E, 0.0f);
        float gv = actf(acc1[2], 2.0f, -2.0f * L2E, -1.0f);
        float ov = actf(acc1[3], 1.0f, -L2E, 0.0f);
        float cn = __builtin_fmaf(fv, c, iv * gv);
        float tc = actf(cn, 2.0f, -2.0f * L2E, -1.0f);
        hv = ov * tc;                       // valid in hi lanes: h2(511)
    }

    // epilogue: hi lanes own (batch=colq-8, unit=u) of h2(T-1)
    if (!lo) outl[colq - 8][u] = hv;
    __syncthreads();
    if (tid < BT) {
        float s = fcb[0];
        for (int uu = 0; uu < HH; ++uu) s = __builtin_fmaf(outl[tid][uu], fcw[uu], s);
        out[b0 + tid] = actf(s, 1.0f, -L2E, 0.0f);
    }
#undef BODY
}

extern "C" void kernel_launch(void* const* d_in, const int* in_sizes, int n_in,
                              void* d_out, int out_size, void* d_ws, size_t ws_size,
                              hipStream_t stream) {
    const float* x    = (const float*)d_in[0];
    const float* Wih0 = (const float*)d_in[1];
    const float* Whh0 = (const float*)d_in[2];
    const float* bih0 = (const float*)d_in[3];
    const float* bhh0 = (const float*)d_in[4];
    const float* Wih1 = (const float*)d_in[5];
    const float* Whh1 = (const float*)d_in[6];
    const float* bih1 = (const float*)d_in[7];
    const float* bhh1 = (const float*)d_in[8];
    const float* fcw  = (const float*)d_in[9];
    const float* fcb  = (const float*)d_in[10];
    lstm_kernel<<<2048 / BT, NTHR, 0, stream>>>(x, Wih0, Whh0, bih0, bhh0,
                                                Wih1, Whh1, bih1, bhh1, fcw, fcb,
                                                (float*)d_out);
}